// Round 5
// baseline (561.996 us; speedup 1.0000x reference)
//
#include <hip/hip_runtime.h>
#include <math.h>

#define D 512
#define AS1 __attribute__((address_space(1)))
#define AS3 __attribute__((address_space(3)))

typedef _Float16 f16x8 __attribute__((ext_vector_type(8)));
typedef float f32x4 __attribute__((ext_vector_type(4)));

// ---------------- Transpose: zTb[g][d][kk_swz] = fp16(h[g*32+k][d]) ----------------
__global__ __launch_bounds__(256) void transpose_kernel(
    const float* __restrict__ h, _Float16* __restrict__ zTb, int N)
{
    __shared__ float tile[64][65];
    const int t0 = blockIdx.x * 64;
    const int d0 = blockIdx.y * 64;
    const int tid = threadIdx.x;
    const int r0 = tid >> 4;
    const int c0 = (tid & 15) * 4;
    #pragma unroll
    for (int k = 0; k < 4; k++) {
        int r = r0 + k * 16;
        float4 v = *(const float4*)(h + (size_t)(t0 + r) * D + d0 + c0);
        tile[r][c0] = v.x; tile[r][c0+1] = v.y; tile[r][c0+2] = v.z; tile[r][c0+3] = v.w;
    }
    __syncthreads();
    const int g = (t0 >> 5) + (c0 >> 5);
    const int kk = c0 & 31;
    const int kg = kk >> 3;
    const int sub = kk & 7;
    #pragma unroll
    for (int k = 0; k < 4; k++) {
        int dd = d0 + r0 + k * 16;
        int kks = ((kg + (dd >> 1)) & 3) * 8 + sub;
        union { _Float16 hh[4]; uint2 u2; } pk;
        #pragma unroll
        for (int i = 0; i < 4; i++) pk.hh[i] = (_Float16)tile[c0 + i][r0 + k * 16];
        *(uint2*)(zTb + (size_t)g * 16384 + dd * 32 + kks) = pk.u2;
    }
}

// ---------------- Linear via fp16 MFMA: x16 = fp16(h @ W^T + b) ----------------
__global__ __launch_bounds__(256) void linear_mfma(
    const float* __restrict__ h, const float* __restrict__ W,
    const float* __restrict__ bias, _Float16* __restrict__ x16, int N)
{
    __shared__ _Float16 sA[128 * 72];
    __shared__ _Float16 sB[128 * 72];
    const int tid  = threadIdx.x;
    const int m0 = blockIdx.x * 128;
    const int n0 = blockIdx.y * 128;
    const int wave = tid >> 6, lane = tid & 63;
    const int l15 = lane & 15, quad = lane >> 4;
    const int wm = (wave >> 1) * 64, wn = (wave & 1) * 64;

    f32x4 acc[4][4];
    #pragma unroll
    for (int mi = 0; mi < 4; mi++)
        #pragma unroll
        for (int ni = 0; ni < 4; ni++) acc[mi][ni] = (f32x4){0.f,0.f,0.f,0.f};

    for (int k0 = 0; k0 < D; k0 += 64) {
        __syncthreads();
        #pragma unroll
        for (int i = 0; i < 8; i++) {
            int idx = tid + 256 * i;
            int row = idx >> 4;
            int c4  = (idx & 15) * 4;
            float4 va = *(const float4*)(h + (size_t)(m0 + row) * D + k0 + c4);
            float4 vb = *(const float4*)(W + (size_t)(n0 + row) * D + k0 + c4);
            union { _Float16 hh[4]; uint2 u2; } pa, pb;
            pa.hh[0] = (_Float16)va.x; pa.hh[1] = (_Float16)va.y;
            pa.hh[2] = (_Float16)va.z; pa.hh[3] = (_Float16)va.w;
            pb.hh[0] = (_Float16)vb.x; pb.hh[1] = (_Float16)vb.y;
            pb.hh[2] = (_Float16)vb.z; pb.hh[3] = (_Float16)vb.w;
            *(uint2*)(sA + row * 72 + c4) = pa.u2;
            *(uint2*)(sB + row * 72 + c4) = pb.u2;
        }
        __syncthreads();
        #pragma unroll
        for (int kc = 0; kc < 2; kc++) {
            f16x8 a[4], b[4];
            #pragma unroll
            for (int mi = 0; mi < 4; mi++)
                a[mi] = *(const f16x8*)(sA + (wm + mi*16 + l15)*72 + kc*32 + quad*8);
            #pragma unroll
            for (int ni = 0; ni < 4; ni++)
                b[ni] = *(const f16x8*)(sB + (wn + ni*16 + l15)*72 + kc*32 + quad*8);
            #pragma unroll
            for (int mi = 0; mi < 4; mi++)
                #pragma unroll
                for (int ni = 0; ni < 4; ni++)
                    acc[mi][ni] = __builtin_amdgcn_mfma_f32_16x16x32_f16(a[mi], b[ni], acc[mi][ni], 0, 0, 0);
        }
    }
    float bv[4];
    #pragma unroll
    for (int ni = 0; ni < 4; ni++) bv[ni] = bias[n0 + wn + ni*16 + l15];
    #pragma unroll
    for (int mi = 0; mi < 4; mi++)
        #pragma unroll
        for (int ni = 0; ni < 4; ni++)
            #pragma unroll
            for (int r = 0; r < 4; r++) {
                int row = m0 + wm + mi*16 + quad*4 + r;
                x16[(size_t)row * D + n0 + wn + ni*16 + l15] = (_Float16)(acc[mi][ni][r] + bv[ni]);
            }
}

// ---------------- Flash attention v12: K-dim-split pair waves ----------------
// LDS-bytes fix without role split: wave (g,h) owns q-group g (32 queries, 2
// subtiles) and dim-half h (256 dims).
//  - scores: partial S over dims [h*256, h*256+256); pair waves exchange the
//    opposite subtile's partial through LDS and each softmaxes 16 queries.
//  - PV: O[2][16] = 32q x 256d (its half); each z-frag read ONCE per pair and
//    reused for both q-subtiles.
//  Per-iter block LDS traffic: ~390KB -> ~230KB; all accesses 2-way (free):
//  ybuf stride 536, exchange stride 36 f32, zbuf granule-swizzled.
//  LDS 76.8KB -> 2 blocks/CU (8 waves, 2/SIMD); VGPR ~230 <= 256 cap.
//  Schedule (3 syncthreads):
//   P1: issue z(kb); scores-partial; write opposite-subtile partial -> sx
//   P2: issue y(kb+1); read partner partial; merge+mask+softmax; P,al -> LDS
//       (P overwrites own sx slot -- read-before-write, safe)
//   P3: read P/al; rescale O; PV MFMAs from zbuf
__global__ __launch_bounds__(256, 2) void attn12_kernel(
    const float* __restrict__ h, const _Float16* __restrict__ x16,
    const _Float16* __restrict__ zTb, const int* __restrict__ lens,
    float* __restrict__ out, int N, int B)
{
    // ybuf  [32][536] f16   @ 0      (34,304 B)
    // zbuf  [512][32] swz   @ 34304  (32,768 B)
    // sx/P  4 x 2304 B      @ 67072  ( 9,216 B)  sx: [16][36] f32; P: [16][40] f16
    // albuf [4][16] f32     @ 76288  (   256 B)
    // lbuf  [4][16] f32     @ 76544  (   256 B)
    __shared__ __align__(16) unsigned char smem[76800];
    _Float16* ybuf = (_Float16*)smem;
    _Float16* zbuf = (_Float16*)(smem + 34304);
    float* albuf = (float*)(smem + 76288);
    float* lbuf  = (float*)(smem + 76544);

    const int is64 = (lens[1] == 0 && lens[3] == 0) ? 1 : 0;

    int seg = -1, tile = 0;
    if (B == 16) {
        const int xcd = blockIdx.x & 7;
        const int idx = blockIdx.x >> 3;
        const int sL = 15 - xcd, sS = xcd;
        const int LL = is64 ? lens[2 * sL] : lens[sL];
        const int LS = is64 ? lens[2 * sS] : lens[sS];
        const int ntL = (LL + 63) >> 6;
        const int ntS = (LS + 63) >> 6;
        if (idx < ntL)            { seg = sL; tile = idx; }
        else if (idx < ntL + ntS) { seg = sS; tile = idx - ntL; }
        else return;
    } else {
        int blk = blockIdx.x;
        int acc = 0;
        for (int t = 0; t < B; t++) {
            int s = B - 1 - t;
            int Ls = is64 ? lens[2 * s] : lens[s];
            int nt = (Ls + 63) >> 6;
            if (seg < 0 && blk < acc + nt) { seg = s; tile = blk - acc; }
            acc += nt;
        }
        if (seg < 0) return;
    }
    int off = 0;
    for (int t = 0; t < seg; t++) off += is64 ? lens[2 * t] : lens[t];
    const int len = is64 ? lens[2 * seg] : lens[seg];

    const int tid  = threadIdx.x;
    const int wv   = tid >> 6;
    const int g    = wv >> 1;        // q-group (32 queries)
    const int hh   = wv & 1;         // dim half
    const int lane = tid & 63;
    const int l15  = lane & 15;
    const int quad = lane >> 4;
    const int zcol = ((quad + (l15 >> 1)) & 3) * 8;
    const int nkb  = (len + 31) >> 5;

    // Q fragments: 2 q-subtiles x 8 chunks over dims [hh*256, hh*256+256)
    f16x8 Qf[2][8];
    #pragma unroll
    for (int ts = 0; ts < 2; ts++) {
        int qr = off + tile * 64 + g * 32 + ts * 16 + l15;
        if (qr > N - 1) qr = N - 1;
        const float* hr = h + (size_t)qr * D + hh * 256;
        #pragma unroll
        for (int cc = 0; cc < 8; cc++) {
            float4 u = *(const float4*)(hr + cc * 32 + quad * 8);
            float4 v = *(const float4*)(hr + cc * 32 + quad * 8 + 4);
            f16x8 q;
            q[0] = (_Float16)u.x; q[1] = (_Float16)u.y; q[2] = (_Float16)u.z; q[3] = (_Float16)u.w;
            q[4] = (_Float16)v.x; q[5] = (_Float16)v.y; q[6] = (_Float16)v.z; q[7] = (_Float16)v.w;
            Qf[ts][cc] = q;
        }
    }

    f32x4 O[2][16];
    #pragma unroll
    for (int ts = 0; ts < 2; ts++)
        #pragma unroll
        for (int f = 0; f < 16; f++) O[ts][f] = (f32x4){0.f,0.f,0.f,0.f};
    float mR[4] = {-1e30f,-1e30f,-1e30f,-1e30f};   // subtile hh's 16 queries
    float lR[4] = {0.f,0.f,0.f,0.f};

    // prologue: stage y(0), rows wv*8..wv*8+7
    #pragma unroll
    for (int i = 0; i < 8; i++) {
        int r = wv * 8 + i;
        int gr = off + r; if (gr > N - 1) gr = N - 1;
        const _Float16* gsrc = x16 + (size_t)gr * D + lane * 8;
        __builtin_amdgcn_global_load_lds((const AS1 unsigned int*)gsrc,
                                         (AS3 unsigned int*)(ybuf + r * 536), 16, 0, 0);
    }
    __syncthreads();

    for (int kb = 0; kb < nkb; kb++) {
        // ================= P1: z-issue + partial scores =================
        {
            const _Float16* zsrc = zTb + (size_t)((off + kb * 32) >> 5) * 16384;
            #pragma unroll
            for (int i = 0; i < 8; i++) {
                int co = (wv * 8 + i) * 512 + lane * 8;
                __builtin_amdgcn_global_load_lds((const AS1 unsigned int*)(zsrc + co),
                                                 (AS3 unsigned int*)(zbuf + co), 16, 0, 0);
            }
        }
        f32x4 s[2][2];
        #pragma unroll
        for (int ts = 0; ts < 2; ts++)
            #pragma unroll
            for (int kt = 0; kt < 2; kt++) s[ts][kt] = (f32x4){0.f,0.f,0.f,0.f};
        __builtin_amdgcn_s_setprio(1);
        #pragma unroll
        for (int cc = 0; cc < 8; cc++) {
            const _Float16* yb = ybuf + hh * 256 + cc * 32 + quad * 8;
            f16x8 b0 = *(const f16x8*)(yb + l15 * 536);
            f16x8 b1 = *(const f16x8*)(yb + (16 + l15) * 536);
            s[0][0] = __builtin_amdgcn_mfma_f32_16x16x32_f16(Qf[0][cc], b0, s[0][0], 0, 0, 0);
            s[1][0] = __builtin_amdgcn_mfma_f32_16x16x32_f16(Qf[1][cc], b0, s[1][0], 0, 0, 0);
            s[0][1] = __builtin_amdgcn_mfma_f32_16x16x32_f16(Qf[0][cc], b1, s[0][1], 0, 0, 0);
            s[1][1] = __builtin_amdgcn_mfma_f32_16x16x32_f16(Qf[1][cc], b1, s[1][1], 0, 0, 0);
        }
        __builtin_amdgcn_s_setprio(0);
        // write OPPOSITE subtile's partial for the partner wave
        {
            float* sxw = (float*)(smem + 67072 + (size_t)(g * 2 + (1 - hh)) * 2304);
            #pragma unroll
            for (int kt = 0; kt < 2; kt++)
                #pragma unroll
                for (int r = 0; r < 4; r++)
                    sxw[(quad * 4 + r) * 36 + kt * 16 + l15] = s[1 - hh][kt][r];
        }
        __syncthreads();   // BAR1: z landed; sx visible; ybuf reads done

        // ================= P2: y-issue + merge + softmax =================
        if (kb + 1 < nkb) {
            const int jn = (kb + 1) * 32;
            #pragma unroll
            for (int i = 0; i < 8; i++) {
                int r = wv * 8 + i;
                int gr = off + jn + r; if (gr > N - 1) gr = N - 1;
                const _Float16* gsrc = x16 + (size_t)gr * D + lane * 8;
                __builtin_amdgcn_global_load_lds((const AS1 unsigned int*)gsrc,
                                                 (AS3 unsigned int*)(ybuf + r * 536), 16, 0, 0);
            }
        }
        {
            const float* sxr = (const float*)(smem + 67072 + (size_t)(g * 2 + hh) * 2304);
            f32x4 sm[2];
            #pragma unroll
            for (int kt = 0; kt < 2; kt++)
                #pragma unroll
                for (int r = 0; r < 4; r++)
                    sm[kt][r] = s[hh][kt][r] + sxr[(quad * 4 + r) * 36 + kt * 16 + l15];
            const int kk0 = kb * 32 + l15, kk1 = kb * 32 + 16 + l15;
            #pragma unroll
            for (int r = 0; r < 4; r++) {
                if (kk0 >= len) sm[0][r] = -1e30f;
                if (kk1 >= len) sm[1][r] = -1e30f;
            }
            _Float16* pw = (_Float16*)(smem + 67072 + (size_t)(g * 2 + hh) * 2304);
            #pragma unroll
            for (int r = 0; r < 4; r++) {
                float t = fmaxf(sm[0][r], sm[1][r]);
                t = fmaxf(t, __shfl_xor(t, 1, 16));
                t = fmaxf(t, __shfl_xor(t, 2, 16));
                t = fmaxf(t, __shfl_xor(t, 4, 16));
                t = fmaxf(t, __shfl_xor(t, 8, 16));
                bool upd = (t > mR[r] + 8.0f);       // defer-max THR=8
                float mn = upd ? t : mR[r];
                float al = upd ? __expf(mR[r] - mn) : 1.0f;
                mR[r] = mn;
                float e0 = __expf(sm[0][r] - mn);
                float e1 = __expf(sm[1][r] - mn);
                float ps = e0 + e1;
                ps += __shfl_xor(ps, 1, 16);
                ps += __shfl_xor(ps, 2, 16);
                ps += __shfl_xor(ps, 4, 16);
                ps += __shfl_xor(ps, 8, 16);
                lR[r] = lR[r] * al + ps;
                pw[(quad * 4 + r) * 40 + l15]      = (_Float16)e0;
                pw[(quad * 4 + r) * 40 + 16 + l15] = (_Float16)e1;
                if (l15 == 0) {
                    albuf[(g * 2 + hh) * 16 + quad * 4 + r] = al;
                    if (kb == nkb - 1) lbuf[(g * 2 + hh) * 16 + quad * 4 + r] = 1.0f / lR[r];
                }
            }
        }
        __syncthreads();   // BAR2: y landed; P/al visible

        // ================= P3: PV over own dim half =================
        {
            const _Float16* p0 = (const _Float16*)(smem + 67072 + (size_t)(g * 2 + 0) * 2304);
            const _Float16* p1 = (const _Float16*)(smem + 67072 + (size_t)(g * 2 + 1) * 2304);
            f16x8 pa0 = *(const f16x8*)(p0 + l15 * 40 + quad * 8);
            f16x8 pa1 = *(const f16x8*)(p1 + l15 * 40 + quad * 8);
            f32x4 av0 = *(const f32x4*)(albuf + (g * 2 + 0) * 16 + quad * 4);
            f32x4 av1 = *(const f32x4*)(albuf + (g * 2 + 1) * 16 + quad * 4);
            bool upd = false;
            #pragma unroll
            for (int r = 0; r < 4; r++) upd |= (av0[r] != 1.0f) | (av1[r] != 1.0f);
            if (__ballot(upd)) {
                #pragma unroll
                for (int f = 0; f < 16; f++) { O[0][f] *= av0; O[1][f] *= av1; }
            }
            const _Float16* zb = zbuf + (size_t)hh * 256 * 32 + zcol;
            __builtin_amdgcn_s_setprio(1);
            #pragma unroll
            for (int f = 0; f < 16; f++) {
                f16x8 zf = *(const f16x8*)(zb + (f * 16 + l15) * 32);
                O[0][f] = __builtin_amdgcn_mfma_f32_16x16x32_f16(pa0, zf, O[0][f], 0, 0, 0);
                O[1][f] = __builtin_amdgcn_mfma_f32_16x16x32_f16(pa1, zf, O[1][f], 0, 0, 0);
            }
            __builtin_amdgcn_s_setprio(0);
        }
        __syncthreads();   // BAR3: zbuf free for restage; pbuf free
    }

    // ---- epilogue: every wave writes its 32q x 256d ----
    #pragma unroll
    for (int ts = 0; ts < 2; ts++) {
        f32x4 inv = *(const f32x4*)(lbuf + (g * 2 + ts) * 16 + quad * 4);
        #pragma unroll
        for (int r = 0; r < 4; r++) {
            int qloc = tile * 64 + g * 32 + ts * 16 + quad * 4 + r;
            if (qloc < len) {
                float* orow = out + (size_t)(off + qloc) * D + hh * 256 + l15;
                #pragma unroll
                for (int f = 0; f < 16; f++) orow[f * 16] = O[ts][f][r] * inv[r];
            }
        }
    }
}

extern "C" void kernel_launch(void* const* d_in, const int* in_sizes, int n_in,
                              void* d_out, int out_size, void* d_ws, size_t ws_size,
                              hipStream_t stream) {
    const float* h    = (const float*)d_in[0];
    const float* W    = (const float*)d_in[1];
    const float* bias = (const float*)d_in[2];
    const int*   lens = (const int*)d_in[3];
    float* outp = (float*)d_out;

    const int N = in_sizes[0] / D;                 // 24064
    int B = in_sizes[3]; if (B > 16) B = 16;

    _Float16* x16 = (_Float16*)d_ws;                                  // N*D fp16
    _Float16* zTb = (_Float16*)((char*)d_ws + (size_t)N * D * 2);     // blocked+swizzled z^T

    dim3 g2(N / 64, D / 64);
    transpose_kernel<<<g2, 256, 0, stream>>>(h, zTb, N);

    dim3 g1(N / 128, D / 128);
    linear_mfma<<<g1, 256, 0, stream>>>(h, W, bias, x16, N);

    const int nblk = N / 64 + B;
    attn12_kernel<<<nblk, 256, 0, stream>>>(h, x16, zTb, lens, outp, N, B);
}

// Round 6
// 428.723 us; speedup vs baseline: 1.3109x; 1.3109x over previous
//
#include <hip/hip_runtime.h>
#include <math.h>

#define D 512
#define AS1 __attribute__((address_space(1)))
#define AS3 __attribute__((address_space(3)))

typedef _Float16 f16x8 __attribute__((ext_vector_type(8)));
typedef float f32x4 __attribute__((ext_vector_type(4)));

// ---------------- Transpose: zTb[g][d][kk_swz] = fp16(h[g*32+k][d]) ----------------
__global__ __launch_bounds__(256) void transpose_kernel(
    const float* __restrict__ h, _Float16* __restrict__ zTb, int N)
{
    __shared__ float tile[64][65];
    const int t0 = blockIdx.x * 64;
    const int d0 = blockIdx.y * 64;
    const int tid = threadIdx.x;
    const int r0 = tid >> 4;
    const int c0 = (tid & 15) * 4;
    #pragma unroll
    for (int k = 0; k < 4; k++) {
        int r = r0 + k * 16;
        float4 v = *(const float4*)(h + (size_t)(t0 + r) * D + d0 + c0);
        tile[r][c0] = v.x; tile[r][c0+1] = v.y; tile[r][c0+2] = v.z; tile[r][c0+3] = v.w;
    }
    __syncthreads();
    const int g = (t0 >> 5) + (c0 >> 5);
    const int kk = c0 & 31;
    const int kg = kk >> 3;
    const int sub = kk & 7;
    #pragma unroll
    for (int k = 0; k < 4; k++) {
        int dd = d0 + r0 + k * 16;
        int kks = ((kg + (dd >> 1)) & 3) * 8 + sub;
        union { _Float16 hh[4]; uint2 u2; } pk;
        #pragma unroll
        for (int i = 0; i < 4; i++) pk.hh[i] = (_Float16)tile[c0 + i][r0 + k * 16];
        *(uint2*)(zTb + (size_t)g * 16384 + dd * 32 + kks) = pk.u2;
    }
}

// ---------------- Linear via fp16 MFMA: x16 = fp16(h @ W^T + b) ----------------
__global__ __launch_bounds__(256) void linear_mfma(
    const float* __restrict__ h, const float* __restrict__ W,
    const float* __restrict__ bias, _Float16* __restrict__ x16, int N)
{
    __shared__ _Float16 sA[128 * 72];
    __shared__ _Float16 sB[128 * 72];
    const int tid  = threadIdx.x;
    const int m0 = blockIdx.x * 128;
    const int n0 = blockIdx.y * 128;
    const int wave = tid >> 6, lane = tid & 63;
    const int l15 = lane & 15, quad = lane >> 4;
    const int wm = (wave >> 1) * 64, wn = (wave & 1) * 64;

    f32x4 acc[4][4];
    #pragma unroll
    for (int mi = 0; mi < 4; mi++)
        #pragma unroll
        for (int ni = 0; ni < 4; ni++) acc[mi][ni] = (f32x4){0.f,0.f,0.f,0.f};

    for (int k0 = 0; k0 < D; k0 += 64) {
        __syncthreads();
        #pragma unroll
        for (int i = 0; i < 8; i++) {
            int idx = tid + 256 * i;
            int row = idx >> 4;
            int c4  = (idx & 15) * 4;
            float4 va = *(const float4*)(h + (size_t)(m0 + row) * D + k0 + c4);
            float4 vb = *(const float4*)(W + (size_t)(n0 + row) * D + k0 + c4);
            union { _Float16 hh[4]; uint2 u2; } pa, pb;
            pa.hh[0] = (_Float16)va.x; pa.hh[1] = (_Float16)va.y;
            pa.hh[2] = (_Float16)va.z; pa.hh[3] = (_Float16)va.w;
            pb.hh[0] = (_Float16)vb.x; pb.hh[1] = (_Float16)vb.y;
            pb.hh[2] = (_Float16)vb.z; pb.hh[3] = (_Float16)vb.w;
            *(uint2*)(sA + row * 72 + c4) = pa.u2;
            *(uint2*)(sB + row * 72 + c4) = pb.u2;
        }
        __syncthreads();
        #pragma unroll
        for (int kc = 0; kc < 2; kc++) {
            f16x8 a[4], b[4];
            #pragma unroll
            for (int mi = 0; mi < 4; mi++)
                a[mi] = *(const f16x8*)(sA + (wm + mi*16 + l15)*72 + kc*32 + quad*8);
            #pragma unroll
            for (int ni = 0; ni < 4; ni++)
                b[ni] = *(const f16x8*)(sB + (wn + ni*16 + l15)*72 + kc*32 + quad*8);
            #pragma unroll
            for (int mi = 0; mi < 4; mi++)
                #pragma unroll
                for (int ni = 0; ni < 4; ni++)
                    acc[mi][ni] = __builtin_amdgcn_mfma_f32_16x16x32_f16(a[mi], b[ni], acc[mi][ni], 0, 0, 0);
        }
    }
    float bv[4];
    #pragma unroll
    for (int ni = 0; ni < 4; ni++) bv[ni] = bias[n0 + wn + ni*16 + l15];
    #pragma unroll
    for (int mi = 0; mi < 4; mi++)
        #pragma unroll
        for (int ni = 0; ni < 4; ni++)
            #pragma unroll
            for (int r = 0; r < 4; r++) {
                int row = m0 + wm + mi*16 + quad*4 + r;
                x16[(size_t)row * D + n0 + wn + ni*16 + l15] = (_Float16)(acc[mi][ni][r] + bv[ni]);
            }
}

// ---------------- Flash attention v13: deep double-buffered pipeline ----------
// v8/v9 wave-private structure (QBLK=64, 4 waves, each owns 16 queries x 512d)
// with BOTH staging buffers double-buffered and prefetch issued a full
// iteration ahead:
//   iter kb: issue y(kb+1),z(kb+1) -> buf[cur^1]   (16 DMAs/wave)
//            scores(ybuf[cur]) ; softmax (wave-private, no barrier)
//            PV(zbuf[cur]) ; __syncthreads()       (ONE barrier/iter)
// The barrier's implicit vmcnt(0) drain now waits on loads issued ~1500+
// cycles earlier -> drain ~0, and barriers/iter drop 2 -> 1.
// LDS 137,216 B -> 1 block/CU (intentional: latency is hidden by pipeline
// depth, not occupancy). __launch_bounds__(256,1) -> no VGPR spill risk.
// Race ledger: buf[cur^1] writes at k vs last reads at k-1: k-1's barrier.
//              buf[cur] reads at k vs writes issued at k-1: k-1's barrier+drain.
//              Pw write->read same wave: compiler lgkmcnt (v8-proven).
__global__ __launch_bounds__(256, 1) void attn13_kernel(
    const float* __restrict__ h, const _Float16* __restrict__ x16,
    const _Float16* __restrict__ zTb, const int* __restrict__ lens,
    float* __restrict__ out, int N, int B)
{
    // ybuf[2] : 2 x [32][520] f16 = 2 x 33,280 @ 0
    // zbuf[2] : 2 x [512][32] swz = 2 x 32,768 @ 66,560
    // pbuf    : 4 x [16][40] f16  = 5,120      @ 132,096   (total 137,216)
    __shared__ __align__(16) unsigned char smem[137216];

    const int is64 = (lens[1] == 0 && lens[3] == 0) ? 1 : 0;

    int seg = -1, tile = 0;
    if (B == 16) {
        // XCD-affine: xcd owns segment pair (15-xcd, xcd); keeps the segment's
        // x16/zTb stream in one XCD's L2 (FETCH 227MB -> 48MB, r3-verified).
        const int xcd = blockIdx.x & 7;
        const int idx = blockIdx.x >> 3;
        const int sL = 15 - xcd, sS = xcd;
        const int LL = is64 ? lens[2 * sL] : lens[sL];
        const int LS = is64 ? lens[2 * sS] : lens[sS];
        const int ntL = (LL + 63) >> 6;
        const int ntS = (LS + 63) >> 6;
        if (idx < ntL)            { seg = sL; tile = idx; }
        else if (idx < ntL + ntS) { seg = sS; tile = idx - ntL; }
        else return;
    } else {
        int blk = blockIdx.x;
        int acc = 0;
        for (int t = 0; t < B; t++) {
            int s = B - 1 - t;
            int Ls = is64 ? lens[2 * s] : lens[s];
            int nt = (Ls + 63) >> 6;
            if (seg < 0 && blk < acc + nt) { seg = s; tile = blk - acc; }
            acc += nt;
        }
        if (seg < 0) return;
    }
    int off = 0;
    for (int t = 0; t < seg; t++) off += is64 ? lens[2 * t] : lens[t];
    const int len = is64 ? lens[2 * seg] : lens[seg];

    const int tid  = threadIdx.x;
    const int wv   = tid >> 6;
    const int lane = tid & 63;
    const int l15  = lane & 15;
    const int quad = lane >> 4;
    const int zcol = ((quad + (l15 >> 1)) & 3) * 8;
    const int nkb  = (len + 31) >> 5;

    // Q A-fragments: 16 queries of this wave
    f16x8 Qf[16];
    {
        int qr = off + tile * 64 + wv * 16 + l15;
        if (qr > N - 1) qr = N - 1;
        const float* hr = h + (size_t)qr * D;
        #pragma unroll
        for (int c = 0; c < 16; c++) {
            float4 u = *(const float4*)(hr + c * 32 + quad * 8);
            float4 v = *(const float4*)(hr + c * 32 + quad * 8 + 4);
            f16x8 q;
            q[0] = (_Float16)u.x; q[1] = (_Float16)u.y; q[2] = (_Float16)u.z; q[3] = (_Float16)u.w;
            q[4] = (_Float16)v.x; q[5] = (_Float16)v.y; q[6] = (_Float16)v.z; q[7] = (_Float16)v.w;
            Qf[c] = q;
        }
    }

    f32x4 O[32];
    #pragma unroll
    for (int f = 0; f < 32; f++) O[f] = (f32x4){0.f,0.f,0.f,0.f};
    float mR[4] = {-1e30f,-1e30f,-1e30f,-1e30f};
    float lR[4] = {0.f,0.f,0.f,0.f};

    _Float16* Pw = (_Float16*)(smem + 132096) + wv * 640;

    // ---- prologue: stage y(0) -> ybuf[0], z(0) -> zbuf[0] ----
    {
        #pragma unroll
        for (int i = 0; i < 8; i++) {
            int r = wv * 8 + i;
            int gr = off + r; if (gr > N - 1) gr = N - 1;
            const _Float16* gsrc = x16 + (size_t)gr * D + lane * 8;
            __builtin_amdgcn_global_load_lds((const AS1 unsigned int*)gsrc,
                                             (AS3 unsigned int*)((_Float16*)smem + r * 520), 16, 0, 0);
        }
        const _Float16* zsrc = zTb + (size_t)(off >> 5) * 16384;
        _Float16* zdst = (_Float16*)(smem + 66560);
        #pragma unroll
        for (int i = 0; i < 8; i++) {
            int co = (wv * 8 + i) * 512 + lane * 8;
            __builtin_amdgcn_global_load_lds((const AS1 unsigned int*)(zsrc + co),
                                             (AS3 unsigned int*)(zdst + co), 16, 0, 0);
        }
    }
    __syncthreads();   // y(0), z(0) resident

    for (int kb = 0; kb < nkb; kb++) {
        const int cur = kb & 1;
        const int nxt = cur ^ 1;
        _Float16* ybuf = (_Float16*)(smem + (size_t)cur * 33280);
        _Float16* zbuf = (_Float16*)(smem + 66560 + (size_t)cur * 32768);

        // ---- issue next-tile DMAs (land during this whole iteration) ----
        if (kb + 1 < nkb) {
            const int jn = (kb + 1) * 32;
            _Float16* ydst = (_Float16*)(smem + (size_t)nxt * 33280);
            #pragma unroll
            for (int i = 0; i < 8; i++) {
                int r = wv * 8 + i;
                int gr = off + jn + r; if (gr > N - 1) gr = N - 1;
                const _Float16* gsrc = x16 + (size_t)gr * D + lane * 8;
                __builtin_amdgcn_global_load_lds((const AS1 unsigned int*)gsrc,
                                                 (AS3 unsigned int*)(ydst + r * 520), 16, 0, 0);
            }
            const _Float16* zsrc = zTb + (size_t)((off + jn) >> 5) * 16384;
            _Float16* zdst = (_Float16*)(smem + 66560 + (size_t)nxt * 32768);
            #pragma unroll
            for (int i = 0; i < 8; i++) {
                int co = (wv * 8 + i) * 512 + lane * 8;
                __builtin_amdgcn_global_load_lds((const AS1 unsigned int*)(zsrc + co),
                                                 (AS3 unsigned int*)(zdst + co), 16, 0, 0);
            }
        }

        // ---- scores from ybuf[cur] ----
        f32x4 s0 = (f32x4){0.f,0.f,0.f,0.f}, s1 = (f32x4){0.f,0.f,0.f,0.f};
        __builtin_amdgcn_s_setprio(1);
        #pragma unroll
        for (int c = 0; c < 16; c++) {
            f16x8 b0 = *(const f16x8*)(ybuf + l15 * 520 + c * 32 + quad * 8);
            f16x8 b1 = *(const f16x8*)(ybuf + (16 + l15) * 520 + c * 32 + quad * 8);
            s0 = __builtin_amdgcn_mfma_f32_16x16x32_f16(Qf[c], b0, s0, 0, 0, 0);
            s1 = __builtin_amdgcn_mfma_f32_16x16x32_f16(Qf[c], b1, s1, 0, 0, 0);
        }
        __builtin_amdgcn_s_setprio(0);
        const int kk0 = kb * 32 + l15, kk1 = kb * 32 + 16 + l15;
        #pragma unroll
        for (int r = 0; r < 4; r++) {
            if (kk0 >= len) s0[r] = -1e30f;
            if (kk1 >= len) s1[r] = -1e30f;
        }

        // ---- online softmax (wave-private, defer-max THR=8) ----
        float al[4];
        bool need = false;
        #pragma unroll
        for (int r = 0; r < 4; r++) {
            float t = fmaxf(s0[r], s1[r]);
            t = fmaxf(t, __shfl_xor(t, 1, 16));
            t = fmaxf(t, __shfl_xor(t, 2, 16));
            t = fmaxf(t, __shfl_xor(t, 4, 16));
            t = fmaxf(t, __shfl_xor(t, 8, 16));
            bool upd = (t > mR[r] + 8.0f);
            float mn = upd ? t : mR[r];
            al[r] = upd ? __expf(mR[r] - mn) : 1.0f;
            mR[r] = mn;
            float e0 = __expf(s0[r] - mn);
            float e1 = __expf(s1[r] - mn);
            float ps = e0 + e1;
            ps += __shfl_xor(ps, 1, 16);
            ps += __shfl_xor(ps, 2, 16);
            ps += __shfl_xor(ps, 4, 16);
            ps += __shfl_xor(ps, 8, 16);
            lR[r] = lR[r] * al[r] + ps;
            Pw[(quad * 4 + r) * 40 + l15]      = (_Float16)e0;
            Pw[(quad * 4 + r) * 40 + 16 + l15] = (_Float16)e1;
            need |= upd;
        }

        // ---- rescale O (rare), read P back (same-wave LDS, lgkmcnt only) ----
        if (__ballot(need)) {
            f32x4 av; av[0] = al[0]; av[1] = al[1]; av[2] = al[2]; av[3] = al[3];
            #pragma unroll
            for (int f = 0; f < 32; f++) O[f] *= av;
        }
        f16x8 pf = *(const f16x8*)(Pw + l15 * 40 + quad * 8);

        // ---- PV from zbuf[cur] (swizzled, conflict-free) ----
        __builtin_amdgcn_s_setprio(1);
        #pragma unroll
        for (int f = 0; f < 32; f++) {
            f16x8 zf = *(const f16x8*)(zbuf + (f * 16 + l15) * 32 + zcol);
            O[f] = __builtin_amdgcn_mfma_f32_16x16x32_f16(pf, zf, O[f], 0, 0, 0);
        }
        __builtin_amdgcn_s_setprio(0);

        __syncthreads();   // ONE barrier: next buffers landed; cur buffers free
    }

    // ---- epilogue ----
    float inv[4];
    #pragma unroll
    for (int r = 0; r < 4; r++) inv[r] = 1.0f / lR[r];
    #pragma unroll
    for (int r = 0; r < 4; r++) {
        int qloc = tile * 64 + wv * 16 + quad * 4 + r;
        if (qloc < len) {
            float* orow = out + (size_t)(off + qloc) * D + l15;
            #pragma unroll
            for (int f = 0; f < 32; f++) orow[f * 16] = O[f][r] * inv[r];
        }
    }
}

extern "C" void kernel_launch(void* const* d_in, const int* in_sizes, int n_in,
                              void* d_out, int out_size, void* d_ws, size_t ws_size,
                              hipStream_t stream) {
    const float* h    = (const float*)d_in[0];
    const float* W    = (const float*)d_in[1];
    const float* bias = (const float*)d_in[2];
    const int*   lens = (const int*)d_in[3];
    float* outp = (float*)d_out;

    const int N = in_sizes[0] / D;                 // 24064
    int B = in_sizes[3]; if (B > 16) B = 16;

    _Float16* x16 = (_Float16*)d_ws;                                  // N*D fp16
    _Float16* zTb = (_Float16*)((char*)d_ws + (size_t)N * D * 2);     // blocked+swizzled z^T

    dim3 g2(N / 64, D / 64);
    transpose_kernel<<<g2, 256, 0, stream>>>(h, zTb, N);

    dim3 g1(N / 128, D / 128);
    linear_mfma<<<g1, 256, 0, stream>>>(h, W, bias, x16, N);

    const int nblk = N / 64 + B;
    attn13_kernel<<<nblk, 256, 0, stream>>>(h, x16, zTb, lens, outp, N, B);
}